// Round 5
// baseline (276.910 us; speedup 1.0000x reference)
//
#include <hip/hip_runtime.h>
#include <hip/hip_bf16.h>

typedef __attribute__((ext_vector_type(8))) short bf16x8;
typedef __attribute__((ext_vector_type(4))) float f32x4;
typedef unsigned short u16;

__device__ __forceinline__ u16 f2bf(float f) {
  __hip_bfloat16 h = __float2bfloat16(f);  // RNE
  u16 u;
  __builtin_memcpy(&u, &h, 2);
  return u;
}
__device__ __forceinline__ void cvt4_store(u16* dst, float4 v) {
  u16 rr[4] = {f2bf(v.x), f2bf(v.y), f2bf(v.z), f2bf(v.w)};
  uint2 p;
  __builtin_memcpy(&p, rr, 8);
  *(uint2*)dst = p;  // 8B-aligned by construction
}
__device__ __forceinline__ bf16x8 pack8(float4 a, float4 b) {
  u16 h[8] = {f2bf(a.x), f2bf(a.y), f2bf(a.z), f2bf(a.w),
              f2bf(b.x), f2bf(b.y), f2bf(b.z), f2bf(b.w)};
  bf16x8 r;
  __builtin_memcpy(&r, h, 16);
  return r;
}

// Dims: B=64, C=512, NE=80, NI=20, E=512. fp32 I/O, bf16 MFMA compute.
// ROUND 5: 8 independent barrier domains per CU, traffic-flat.
// Evidence r0-r4: delivered BW scales with independent blocks/CU
// (2 dom -> 2.4 TB/s, 4 dom -> 3.5 TB/s); loaded latency ~7.7us (r4's
// 15-step pipeline); wave count & intra-block pipelining ~no effect.
// Split: grid (512 c, 2 oh, 2 bh) x 128 thr = 2048 blocks = 8/CU resident.
//   oh=0: e-col-tiles 0..2 ; oh=1: e-col-tiles 3,4 + i-col-tiles 0,1.
//   bh: batches bh*32..+31 (2 waves = 2 m-tiles of 16).
// Weight rows disjoint across oh (no dup); inc rows disjoint across bh.
// Dup reads (inc x2 across oh, in_proj x2 across bh, small state) are
// between siblings with linear ids differing by 512/1024 = 0 mod 8 ->
// SAME XCD -> L2-filtered; all 2048 blocks resident -> filtering by
// concurrency. HBM traffic stays ~115 MB.
// MFMA 16x16x32: a A[m=lane&15][k=quad*8+j], b Bt[n=lane&15][k=...],
// C/D C[m=quad*4+reg][n=lane&15] (m89/m91).
// LDS 18432B (8 x 18.4KB = 147KB/CU); launch_bounds(128,4) -> VGPR<=128.

__global__ __launch_bounds__(128, 4) void ei_cols_mfma(
    const float* __restrict__ thal,     // [64][512]
    const float* __restrict__ inc,      // [64][512][512]
    const float* __restrict__ l23,      // [64][512][80]
    const float* __restrict__ re_in,    // [64][512][80]
    const float* __restrict__ ri_in,    // [64][512][20]
    const float* __restrict__ ev_in,    // [64][512][80]
    const float* __restrict__ iv_in,    // [64][512][20]
    const float* __restrict__ in_proj,  // [512][80][512]
    const float* __restrict__ fb_proj,  // [512][80][80]
    const float* __restrict__ w_ee,     // [512][80][80]
    const float* __restrict__ w_ei,     // [512][20][80]
    const float* __restrict__ w_ie,     // [512][80][20]
    float* __restrict__ out)            // r_e|r_i|v_e|v_i flat fp32
{
  // LDS: [0,4608) A buf0 [32][72]bf16 ; [4608,9216) A buf1 ;
  //      [9216,15872) As [32][104]bf16 (l23, then re) ;
  //      [15872,18432) Ri [32][40]bf16 (zero-padded cols 20..39).
  __shared__ __align__(16) unsigned char smem[18432];
  const int c = blockIdx.x;
  const int oh = blockIdx.y;          // output-tile half
  const int bh32 = blockIdx.z * 32;   // batch-half base
  const int tid = threadIdx.x;        // 0..127
  const int lane = tid & 63;
  const int wave = tid >> 6;          // 0,1 -> m-tile within the half
  const int nidx = lane & 15;
  const int quad = lane >> 4;
  const int q8 = quad * 8;
  const int lrow = wave * 16 + nidx;  // row within the 32-row LDS tiles

  f32x4 acc_e[3], acc_i[2];
#pragma unroll
  for (int j = 0; j < 3; ++j) acc_e[j] = (f32x4){0.f, 0.f, 0.f, 0.f};
#pragma unroll
  for (int j = 0; j < 2; ++j) acc_i[j] = (f32x4){0.f, 0.f, 0.f, 0.f};

  const float* wA = in_proj + (size_t)c * 40960;

  // ---- Phase A: I_ext = (thal+inc).in_proj^T, K=512, double-buffered -----
  float4 tv[4], gv[4];
  float4 fbv[5];  // l23 prefetch (iter 5), stored to As at iter 7

  auto load_regs = [&](int k0) {
#pragma unroll
    for (int j = 0; j < 4; ++j) {
      int l = tid + j * 128;
      int b = l >> 4, kk = (l & 15) << 2;
      tv[j] = *(const float4*)(thal + (bh32 + b) * 512 + k0 + kk);
      gv[j] = *(const float4*)(inc + (size_t)(bh32 + b) * 262144 +
                               (size_t)c * 512 + k0 + kk);
    }
  };
  auto store_buf = [&](int p) {
    u16* A = (u16*)(smem + p * 4608);
#pragma unroll
    for (int j = 0; j < 4; ++j) {
      int l = tid + j * 128;
      int b = l >> 4, kk = (l & 15) << 2;
      float4 s;
      s.x = tv[j].x + gv[j].x; s.y = tv[j].y + gv[j].y;
      s.z = tv[j].z + gv[j].z; s.w = tv[j].w + gv[j].w;
      cvt4_store(A + b * 72 + kk, s);
    }
  };

  load_regs(0);
  store_buf(0);
  for (int i = 0; i < 8; ++i) {
    __syncthreads();
    if (i < 7) load_regs((i + 1) * 64);
    if (i == 5) {  // prefetch l23 for phase B (32 rows x 80 = 640 f4)
#pragma unroll
      for (int j = 0; j < 5; ++j) {
        int l = tid + j * 128;
        int b = l / 20, kk = (l % 20) << 2;
        fbv[j] = *(const float4*)(l23 + ((size_t)(bh32 + b) * 512 + c) * 80 + kk);
      }
    }
    if (i == 7) {  // store l23 -> As (region disjoint from A bufs)
      u16* As = (u16*)(smem + 9216);
#pragma unroll
      for (int j = 0; j < 5; ++j) {
        int l = tid + j * 128;
        int b = l / 20, kk = (l % 20) << 2;
        cvt4_store(As + b * 104 + kk, fbv[j]);
      }
    }
    const u16* A = (const u16*)(smem + (i & 1) * 4608);
    const float* wb = wA + i * 64;
#pragma unroll
    for (int kk0 = 0; kk0 < 64; kk0 += 32) {
      bf16x8 a = *(const bf16x8*)(A + lrow * 72 + kk0 + q8);
      if (oh == 0) {
#pragma unroll
        for (int j = 0; j < 3; ++j) {
          const float* p = wb + (size_t)(j * 16 + nidx) * 512 + kk0 + q8;
          bf16x8 b = pack8(*(const float4*)p, *(const float4*)(p + 4));
          acc_e[j] = __builtin_amdgcn_mfma_f32_16x16x32_bf16(a, b, acc_e[j], 0, 0, 0);
        }
      } else {
#pragma unroll
        for (int j = 0; j < 2; ++j) {
          const float* p = wb + (size_t)((3 + j) * 16 + nidx) * 512 + kk0 + q8;
          bf16x8 b = pack8(*(const float4*)p, *(const float4*)(p + 4));
          acc_e[j] = __builtin_amdgcn_mfma_f32_16x16x32_bf16(a, b, acc_e[j], 0, 0, 0);
        }
      }
    }
    if (i < 7) store_buf((i + 1) & 1);
  }

  // ---- Phase B: I_fb = l23 . fb_proj^T, K=80 (tail-masked) ---------------
  float4 rev[5];  // re prefetch for phase C (hides under B k-loop)
#pragma unroll
  for (int j = 0; j < 5; ++j) {
    int l = tid + j * 128;
    int b = l / 20, kk = (l % 20) << 2;
    rev[j] = *(const float4*)(re_in + ((size_t)(bh32 + b) * 512 + c) * 80 + kk);
  }
  __syncthreads();  // As(l23) ready
  {
    const u16* As = (const u16*)(smem + 9216);
    const float* fb = fb_proj + (size_t)c * 6400;
#pragma unroll
    for (int kk0 = 0; kk0 < 96; kk0 += 32) {
      const bool full = (kk0 < 64) || (quad < 2);
      bf16x8 a = {0, 0, 0, 0, 0, 0, 0, 0};
      if (full) a = *(const bf16x8*)(As + lrow * 104 + kk0 + q8);
      if (oh == 0) {
#pragma unroll
        for (int j = 0; j < 3; ++j) {
          float4 w0 = {0.f, 0.f, 0.f, 0.f}, w1 = {0.f, 0.f, 0.f, 0.f};
          if (full) {
            const float* p = fb + (size_t)(j * 16 + nidx) * 80 + kk0 + q8;
            w0 = *(const float4*)p; w1 = *(const float4*)(p + 4);
          }
          bf16x8 b = pack8(w0, w1);
          acc_e[j] = __builtin_amdgcn_mfma_f32_16x16x32_bf16(a, b, acc_e[j], 0, 0, 0);
        }
      } else {
#pragma unroll
        for (int j = 0; j < 2; ++j) {
          float4 w0 = {0.f, 0.f, 0.f, 0.f}, w1 = {0.f, 0.f, 0.f, 0.f};
          if (full) {
            const float* p = fb + (size_t)((3 + j) * 16 + nidx) * 80 + kk0 + q8;
            w0 = *(const float4*)p; w1 = *(const float4*)(p + 4);
          }
          bf16x8 b = pack8(w0, w1);
          acc_e[j] = __builtin_amdgcn_mfma_f32_16x16x32_bf16(a, b, acc_e[j], 0, 0, 0);
        }
      }
    }
  }

  // ---- Phase C: I_ee = r_e.W_ee^T ; I_ei = r_e.W_ei^T (oh=1) -------------
  __syncthreads();  // all waves done reading As(l23)
  {
    u16* Asw = (u16*)(smem + 9216);
#pragma unroll
    for (int j = 0; j < 5; ++j) {
      int l = tid + j * 128;
      int b = l / 20, kk = (l % 20) << 2;
      cvt4_store(Asw + b * 104 + kk, rev[j]);
    }
  }
  float4 riv[2];  // ri prefetch for phase D (32 rows x 20 = 160 f4)
#pragma unroll
  for (int j = 0; j < 2; ++j) {
    int l = tid + j * 128;
    if (l < 160) {
      int b = l / 5, kk = (l % 5) << 2;
      riv[j] = *(const float4*)(ri_in + ((size_t)(bh32 + b) * 512 + c) * 20 + kk);
    }
  }
  __syncthreads();  // As(re) ready
  {
    const u16* As = (const u16*)(smem + 9216);
    const float* wee = w_ee + (size_t)c * 6400;
    const float* wei = w_ei + (size_t)c * 1600;
#pragma unroll
    for (int kk0 = 0; kk0 < 96; kk0 += 32) {
      const bool full = (kk0 < 64) || (quad < 2);
      bf16x8 a = {0, 0, 0, 0, 0, 0, 0, 0};
      if (full) a = *(const bf16x8*)(As + lrow * 104 + kk0 + q8);
      if (oh == 0) {
#pragma unroll
        for (int j = 0; j < 3; ++j) {
          float4 w0 = {0.f, 0.f, 0.f, 0.f}, w1 = {0.f, 0.f, 0.f, 0.f};
          if (full) {
            const float* p = wee + (size_t)(j * 16 + nidx) * 80 + kk0 + q8;
            w0 = *(const float4*)p; w1 = *(const float4*)(p + 4);
          }
          bf16x8 b = pack8(w0, w1);
          acc_e[j] = __builtin_amdgcn_mfma_f32_16x16x32_bf16(a, b, acc_e[j], 0, 0, 0);
        }
      } else {
#pragma unroll
        for (int j = 0; j < 2; ++j) {
          float4 w0 = {0.f, 0.f, 0.f, 0.f}, w1 = {0.f, 0.f, 0.f, 0.f};
          if (full) {
            const float* p = wee + (size_t)((3 + j) * 16 + nidx) * 80 + kk0 + q8;
            w0 = *(const float4*)p; w1 = *(const float4*)(p + 4);
          }
          bf16x8 b = pack8(w0, w1);
          acc_e[j] = __builtin_amdgcn_mfma_f32_16x16x32_bf16(a, b, acc_e[j], 0, 0, 0);
        }
#pragma unroll
        for (int j = 0; j < 2; ++j) {
          const int row = j * 16 + nidx;
          float4 w0 = {0.f, 0.f, 0.f, 0.f}, w1 = {0.f, 0.f, 0.f, 0.f};
          if (row < 20 && full) {
            const float* p = wei + (size_t)row * 80 + kk0 + q8;
            w0 = *(const float4*)p; w1 = *(const float4*)(p + 4);
          }
          bf16x8 b = pack8(w0, w1);
          acc_i[j] = __builtin_amdgcn_mfma_f32_16x16x32_bf16(a, b, acc_i[j], 0, 0, 0);
        }
      }
    }
  }

  // ---- Phase D: I_ie = r_i . (-W_ie)^T, K=20 (pad 32) --------------------
  __syncthreads();  // all waves done reading As(re)
  {
    u16* Ri = (u16*)(smem + 15872);
#pragma unroll
    for (int j = 0; j < 2; ++j) {
      int l = tid + j * 128;
      if (l < 160) {
        int b = l / 5, kk = (l % 5) << 2;
        cvt4_store(Ri + b * 40 + kk, riv[j]);
      }
    }
#pragma unroll
    for (int j = 0; j < 2; ++j) {  // zero-pad cols 20..39 (k >= 20)
      int l = tid + j * 128;
      if (l < 160) {
        int b = l / 5, off = 20 + (l % 5) * 4;
        *(uint2*)(Ri + b * 40 + off) = (uint2){0u, 0u};
      }
    }
  }
  // Epilogue state loads: latency hides under barrier drain + D MFMA.
  float evr[3][4], ivr[2][4];
  const int row0 = bh32 + wave * 16 + quad * 4;
  if (oh == 0) {
#pragma unroll
    for (int j = 0; j < 3; ++j) {
      int col = j * 16 + nidx;
#pragma unroll
      for (int r = 0; r < 4; ++r)
        evr[j][r] = ev_in[((size_t)(row0 + r) * 512 + c) * 80 + col];
    }
  } else {
#pragma unroll
    for (int j = 0; j < 2; ++j) {
      int col = 48 + j * 16 + nidx;
#pragma unroll
      for (int r = 0; r < 4; ++r)
        evr[j][r] = ev_in[((size_t)(row0 + r) * 512 + c) * 80 + col];
    }
#pragma unroll
    for (int j = 0; j < 2; ++j) {
      int col = j * 16 + nidx;
#pragma unroll
      for (int r = 0; r < 4; ++r)
        ivr[j][r] = (col < 20)
            ? iv_in[((size_t)(row0 + r) * 512 + c) * 20 + col] : 0.f;
    }
  }
  __syncthreads();  // Ri ready
  {
    const u16* Ri = (const u16*)(smem + 15872);
    bf16x8 a = *(const bf16x8*)(Ri + lrow * 40 + q8);  // pads are real zeros
    auto wieF = [&](int row) -> bf16x8 {
      const float* p = w_ie + (size_t)c * 1600 + row * 20 + q8;
      float4 w0 = {0.f, 0.f, 0.f, 0.f}, w1 = {0.f, 0.f, 0.f, 0.f};
      if (quad < 2) { w0 = *(const float4*)p; w1 = *(const float4*)(p + 4); }
      else if (quad == 2) { w0 = *(const float4*)p; }
      w0.x = -w0.x; w0.y = -w0.y; w0.z = -w0.z; w0.w = -w0.w;
      w1.x = -w1.x; w1.y = -w1.y; w1.z = -w1.z; w1.w = -w1.w;
      return pack8(w0, w1);
    };
    if (oh == 0) {
#pragma unroll
      for (int j = 0; j < 3; ++j) {
        bf16x8 b = wieF(j * 16 + nidx);
        acc_e[j] = __builtin_amdgcn_mfma_f32_16x16x32_bf16(a, b, acc_e[j], 0, 0, 0);
      }
    } else {
#pragma unroll
      for (int j = 0; j < 2; ++j) {
        bf16x8 b = wieF((3 + j) * 16 + nidx);
        acc_e[j] = __builtin_amdgcn_mfma_f32_16x16x32_bf16(a, b, acc_e[j], 0, 0, 0);
      }
    }
  }

  // ---- Epilogue: v = v_old + 0.1*(I - v_old) ; r = relu(v), direct -------
  // C/D mapping: row = bh32 + wave*16 + quad*4 + r, col = tile*16 + nidx.
  {
    const size_t R_ri = 2621440u;
    const size_t R_ve = 3276800u;
    const size_t R_vi = 5898240u;
    if (oh == 0) {
#pragma unroll
      for (int j = 0; j < 3; ++j) {
        const int col = j * 16 + nidx;
#pragma unroll
        for (int r = 0; r < 4; ++r) {
          size_t g = ((size_t)(row0 + r) * 512 + c) * 80 + col;
          float e0 = evr[j][r];
          float v = e0 + 0.1f * (acc_e[j][r] - e0);
          out[g] = fmaxf(v, 0.f);
          out[R_ve + g] = v;
        }
      }
    } else {
#pragma unroll
      for (int j = 0; j < 2; ++j) {
        const int col = 48 + j * 16 + nidx;
#pragma unroll
        for (int r = 0; r < 4; ++r) {
          size_t g = ((size_t)(row0 + r) * 512 + c) * 80 + col;
          float e0 = evr[j][r];
          float v = e0 + 0.1f * (acc_e[j][r] - e0);
          out[g] = fmaxf(v, 0.f);
          out[R_ve + g] = v;
        }
      }
#pragma unroll
      for (int j = 0; j < 2; ++j) {
        const int col = j * 16 + nidx;
        if (col < 20) {
#pragma unroll
          for (int r = 0; r < 4; ++r) {
            size_t g = ((size_t)(row0 + r) * 512 + c) * 20 + col;
            float i0 = ivr[j][r];
            float v = i0 + 0.1f * (acc_i[j][r] - i0);
            out[R_ri + g] = fmaxf(v, 0.f);
            out[R_vi + g] = v;
          }
        }
      }
    }
  }
}

extern "C" void kernel_launch(void* const* d_in, const int* in_sizes, int n_in,
                              void* d_out, int out_size, void* d_ws, size_t ws_size,
                              hipStream_t stream) {
  const float* thal = (const float*)d_in[0];
  const float* inc = (const float*)d_in[1];
  const float* l23 = (const float*)d_in[2];
  const float* re = (const float*)d_in[3];
  const float* ri = (const float*)d_in[4];
  const float* ev = (const float*)d_in[5];
  const float* iv = (const float*)d_in[6];
  const float* in_proj = (const float*)d_in[7];
  const float* fb_proj = (const float*)d_in[8];
  const float* w_ee = (const float*)d_in[9];
  const float* w_ei = (const float*)d_in[10];
  const float* w_ie = (const float*)d_in[11];
  float* out = (float*)d_out;
  ei_cols_mfma<<<dim3(512, 2, 2), dim3(128), 0, stream>>>(
      thal, inc, l23, re, ri, ev, iv, in_proj, fb_proj, w_ee, w_ei, w_ie, out);
}